// Round 5
// baseline (430.788 us; speedup 1.0000x reference)
//
#include <hip/hip_runtime.h>
#include <math.h>

constexpr int HD    = 32;     // head dim
constexpr int LW    = 256;    // tokens per window (M * N_CAND)
constexpr int NWIN  = 128;    // number of windows (= B_)
constexpr int ROWS  = NWIN * LW;   // 32768 total rows
constexpr int QKVC  = 384;    // qkv columns
constexpr float SCALE = 0.17677669529663687f;  // 1/sqrt(32)

__device__ inline float dot4(const float4 a, const float4 b) {
  return a.x * b.x + a.y * b.y + a.z * b.z + a.w * b.w;
}

// ---------------- RPE gather: rpe_g[h][i4*64+j4][0:96] ----------------
// s in [0,32): scale*q_rpe   [32,64): k_rpe   [64,96): v_rpe
__global__ __launch_bounds__(256) void rpe_gather_kernel(
    const float* __restrict__ tab, const int* __restrict__ rel_idx,
    float* __restrict__ out)
{
  int gid = blockIdx.x * 256 + threadIdx.x;   // 4*4096*96 = 1,572,864 exact
  int s   = gid % 96;
  int hp  = gid / 96;
  int p   = hp & 4095;
  int h   = hp >> 12;
  float v = tab[(size_t)rel_idx[p] * 384 + h * 96 + s];
  if (s < 32) v *= SCALE;
  out[gid] = v;
}

// ---------------- C[M,N] = A[M,K] @ W[N,K]^T + bias (LDS dbuf v3) -----------
// BM=BN=128, BK=8, 256 threads, 8x8 micro-tile.
// LDS tiles transposed [k][phys(m)], phys(m)=m+(m>>5)*4. No launch-bounds cap
// (v2's 64-VGPR spill lesson).
template <int N, int K>
__global__ __launch_bounds__(256) void gemm_nt_bias_v3(
    const float* __restrict__ A, const float* __restrict__ W,
    const float* __restrict__ bias, float* __restrict__ C)
{
  constexpr int BK  = 8;
  constexpr int NS  = K / BK;
  constexpr int LDP = 144;
  __shared__ float As[2][BK][LDP];
  __shared__ float Ws[2][BK][LDP];

  const int tid  = threadIdx.x;
  const int tx   = tid & 15;          // n-dir, 8 cols each
  const int ty   = tid >> 4;          // m-dir, 8 rows each
  const int srow = tid >> 1;          // staging row 0..127
  const int skk  = (tid & 1) << 2;    // staging k base: 0 or 4
  const int sphys = srow + ((srow >> 5) << 2);

  const float* Ag = A + ((size_t)blockIdx.x * 128 + srow) * K + skk;
  const float* Wg = W + ((size_t)blockIdx.y * 128 + srow) * K + skk;

  float4 ra = *(const float4*)(Ag);
  float4 rw = *(const float4*)(Wg);
  As[0][skk + 0][sphys] = ra.x; As[0][skk + 1][sphys] = ra.y;
  As[0][skk + 2][sphys] = ra.z; As[0][skk + 3][sphys] = ra.w;
  Ws[0][skk + 0][sphys] = rw.x; Ws[0][skk + 1][sphys] = rw.y;
  Ws[0][skk + 2][sphys] = rw.z; Ws[0][skk + 3][sphys] = rw.w;
  __syncthreads();

  const int mA = ty * 8; const int pA = mA + ((mA >> 5) << 2);
  const int mB = tx * 8; const int pB = mB + ((mB >> 5) << 2);

  float acc[8][8] = {};

  for (int s = 0; s < NS; ++s) {
    const int cur = s & 1;
    if (s + 1 < NS) {
      const int k0 = (s + 1) * BK;
      ra = *(const float4*)(Ag + k0);
      rw = *(const float4*)(Wg + k0);
    }
#pragma unroll
    for (int k = 0; k < BK; ++k) {
      float4 a0 = *(const float4*)&As[cur][k][pA];
      float4 a1 = *(const float4*)&As[cur][k][pA + 4];
      float4 b0 = *(const float4*)&Ws[cur][k][pB];
      float4 b1 = *(const float4*)&Ws[cur][k][pB + 4];
      float av[8] = {a0.x, a0.y, a0.z, a0.w, a1.x, a1.y, a1.z, a1.w};
      float bv[8] = {b0.x, b0.y, b0.z, b0.w, b1.x, b1.y, b1.z, b1.w};
#pragma unroll
      for (int i = 0; i < 8; ++i)
#pragma unroll
        for (int j = 0; j < 8; ++j)
          acc[i][j] += av[i] * bv[j];
    }
    if (s + 1 < NS) {
      const int nxt = (s + 1) & 1;
      As[nxt][skk + 0][sphys] = ra.x; As[nxt][skk + 1][sphys] = ra.y;
      As[nxt][skk + 2][sphys] = ra.z; As[nxt][skk + 3][sphys] = ra.w;
      Ws[nxt][skk + 0][sphys] = rw.x; Ws[nxt][skk + 1][sphys] = rw.y;
      Ws[nxt][skk + 2][sphys] = rw.z; Ws[nxt][skk + 3][sphys] = rw.w;
      __syncthreads();
    }
  }

  const int crow = blockIdx.x * 128 + ty * 8;
  const int ccol = blockIdx.y * 128 + tx * 8;
  float4 bb0 = *(const float4*)(bias + ccol);
  float4 bb1 = *(const float4*)(bias + ccol + 4);
#pragma unroll
  for (int i = 0; i < 8; ++i) {
    float4 r0, r1;
    r0.x = acc[i][0] + bb0.x; r0.y = acc[i][1] + bb0.y;
    r0.z = acc[i][2] + bb0.z; r0.w = acc[i][3] + bb0.w;
    r1.x = acc[i][4] + bb1.x; r1.y = acc[i][5] + bb1.y;
    r1.z = acc[i][6] + bb1.z; r1.w = acc[i][7] + bb1.w;
    *(float4*)(C + (size_t)(crow + i) * N + ccol)     = r0;
    *(float4*)(C + (size_t)(crow + i) * N + ccol + 4) = r1;
  }
}

// ---------------- fused window attention v4: in-block j-split --------------
// grid (NWIN, 4 heads), 512 threads (8 waves): thread = (row, jhalf).
// Each half computes 32 of 64 j4-groups; softmax is max-free (scores O(1),
// masked -> exp underflow to 0) so partials merge by pure summation in LDS.
// Grid was the occupancy cap before (512 blocks * 4 waves = 8 waves/CU);
// 512-thread blocks give 16 waves/CU with the same 64 KB full-window K/V.
__global__ __launch_bounds__(512) void attn_kernel(
    const float* __restrict__ qkv, const float* __restrict__ rpeg,
    const float* __restrict__ mask, float* __restrict__ out)
{
  __shared__ float kvs[2 * LW * HD];   // K[256][32] then V[256][32], 64 KB
  const int b = blockIdx.x;
  const int h = blockIdx.y;
  const int tid = threadIdx.x;
  const int row = tid & 255;
  const int jh  = tid >> 8;            // 0 or 1 (wave-uniform)
  const size_t rowbase = (size_t)b * LW;

  // stage K/V: 4096 float4, 8 per thread, LDS-contiguous (2-way = free)
#pragma unroll
  for (int it = 0; it < 8; ++it) {
    const int f  = tid + 512 * it;     // 0..4095
    const int kv = f >> 11;            // 0 = K, 1 = V
    const int rr = f & 2047;
    const int j  = rr >> 3, d4 = rr & 7;
    *(float4*)(&kvs[f * 4]) =
        *(const float4*)(qkv + (rowbase + j) * QKVC + 128 + kv * 128 +
                         h * HD + d4 * 4);
  }

  float4 q[8];
  {
    const float4* qr = (const float4*)(qkv + (rowbase + row) * QKVC + h * HD);
#pragma unroll
    for (int d = 0; d < 8; ++d) {
      float4 t = qr[d];
      q[d] = make_float4(t.x * SCALE, t.y * SCALE, t.z * SCALE, t.w * SCALE);
    }
  }
  __syncthreads();

  const float4* rp4base =
      (const float4*)(rpeg + ((size_t)h * 4096 + (size_t)(row >> 2) * 64) * 96);
  const float* mrow = mask + ((size_t)b * LW + row) * LW;

  float4 acc[8];
#pragma unroll
  for (int d = 0; d < 8; ++d) acc[d] = make_float4(0.f, 0.f, 0.f, 0.f);
  float l_run = 0.f;

  for (int l = 0; l < 32; ++l) {
    const int j4 = jh * 32 + l;
    const float4* rp = rp4base + j4 * 24;   // sq_rpe[0:8] | k_rpe[8:16] | v_rpe[16:24]
    float4 mv = *(const float4*)(mrow + j4 * 4);
    const float4* k0 = (const float4*)(&kvs[(j4 * 4 + 0) * HD]);
    const float4* k1 = (const float4*)(&kvs[(j4 * 4 + 1) * HD]);
    const float4* k2 = (const float4*)(&kvs[(j4 * 4 + 2) * HD]);
    const float4* k3 = (const float4*)(&kvs[(j4 * 4 + 3) * HD]);
    float c0 = 0.f;
    float s0 = mv.x, s1 = mv.y, s2 = mv.z, s3 = mv.w;
#pragma unroll
    for (int d = 0; d < 8; ++d) {
      float4 sq = rp[d];
      float4 kr = rp[8 + d];
      float4 uq = make_float4(q[d].x + sq.x, q[d].y + sq.y,
                              q[d].z + sq.z, q[d].w + sq.w);
      c0 += dot4(q[d], kr);
      s0 += dot4(uq, k0[d]);
      s1 += dot4(uq, k1[d]);
      s2 += dot4(uq, k2[d]);
      s3 += dot4(uq, k3[d]);
    }
    float p0 = __expf(s0 + c0), p1 = __expf(s1 + c0);
    float p2 = __expf(s2 + c0), p3 = __expf(s3 + c0);
    float pool = (p0 + p1) + (p2 + p3);
    l_run += pool;
    const float4* v0 = (const float4*)(&kvs[LW * HD + (j4 * 4 + 0) * HD]);
    const float4* v1 = (const float4*)(&kvs[LW * HD + (j4 * 4 + 1) * HD]);
    const float4* v2 = (const float4*)(&kvs[LW * HD + (j4 * 4 + 2) * HD]);
    const float4* v3 = (const float4*)(&kvs[LW * HD + (j4 * 4 + 3) * HD]);
#pragma unroll
    for (int d = 0; d < 8; ++d) {
      float4 vr = rp[16 + d];
      float4 a = acc[d];
      a.x += p0 * v0[d].x + p1 * v1[d].x + p2 * v2[d].x + p3 * v3[d].x + pool * vr.x;
      a.y += p0 * v0[d].y + p1 * v1[d].y + p2 * v2[d].y + p3 * v3[d].y + pool * vr.y;
      a.z += p0 * v0[d].z + p1 * v1[d].z + p2 * v2[d].z + p3 * v3[d].z + pool * vr.z;
      a.w += p0 * v0[d].w + p1 * v1[d].w + p2 * v2[d].w + p3 * v3[d].w + pool * vr.w;
      acc[d] = a;
    }
  }

  // merge halves via LDS (stride 33: bank = (row + c) % 32, conflict-free)
  __syncthreads();
  if (jh == 1) {
    float* dst = &kvs[row * 33];
#pragma unroll
    for (int d = 0; d < 8; ++d) {
      dst[d * 4 + 0] = acc[d].x; dst[d * 4 + 1] = acc[d].y;
      dst[d * 4 + 2] = acc[d].z; dst[d * 4 + 3] = acc[d].w;
    }
    dst[32] = l_run;
  }
  __syncthreads();
  if (jh == 0) {
    const float* src = &kvs[row * 33];
    float inv = 1.f / (l_run + src[32]);
    float4* orow = (float4*)(out + (rowbase + row) * (4 * HD) + h * HD);
#pragma unroll
    for (int d = 0; d < 8; ++d) {
      float4 r;
      r.x = (acc[d].x + src[d * 4 + 0]) * inv;
      r.y = (acc[d].y + src[d * 4 + 1]) * inv;
      r.z = (acc[d].z + src[d * 4 + 2]) * inv;
      r.w = (acc[d].w + src[d * 4 + 3]) * inv;
      orow[d] = r;
    }
  }
}

extern "C" void kernel_launch(void* const* d_in, const int* in_sizes, int n_in,
                              void* d_out, int out_size, void* d_ws, size_t ws_size,
                              hipStream_t stream) {
  (void)in_sizes; (void)n_in; (void)out_size; (void)ws_size;
  const float* x         = (const float*)d_in[0];
  const float* qkv_w     = (const float*)d_in[1];
  const float* qkv_b     = (const float*)d_in[2];
  const float* rpe_table = (const float*)d_in[3];
  const float* proj_w    = (const float*)d_in[4];
  const float* proj_b    = (const float*)d_in[5];
  const float* attn_mask = (const float*)d_in[6];
  const int*   rel_idx   = (const int*)d_in[7];
  float* out = (float*)d_out;

  float* qkvbuf = (float*)d_ws;                          // 32768*384 fp32 (50.3 MB)
  float* rpeg   = qkvbuf + (size_t)ROWS * QKVC;          // 4*4096*96  (6.3 MB)
  float* attnb  = rpeg + (size_t)4 * 4096 * 96;          // 32768*128  (16.8 MB)

  hipLaunchKernelGGL(rpe_gather_kernel, dim3(6144), dim3(256), 0, stream,
                     rpe_table, rel_idx, rpeg);
  hipLaunchKernelGGL((gemm_nt_bias_v3<QKVC, 128>), dim3(ROWS / 128, QKVC / 128),
                     dim3(256), 0, stream, x, qkv_w, qkv_b, qkvbuf);
  hipLaunchKernelGGL(attn_kernel, dim3(NWIN, 4), dim3(512), 0, stream,
                     qkvbuf, rpeg, attn_mask, attnb);
  hipLaunchKernelGGL((gemm_nt_bias_v3<128, 128>), dim3(ROWS / 128, 1),
                     dim3(256), 0, stream, attnb, proj_w, proj_b, out);
}

// Round 6
// 368.059 us; speedup vs baseline: 1.1704x; 1.1704x over previous
//
#include <hip/hip_runtime.h>
#include <math.h>

constexpr int HD    = 32;     // head dim
constexpr int LW    = 256;    // tokens per window (M * N_CAND)
constexpr int NWIN  = 128;    // number of windows (= B_)
constexpr int ROWS  = NWIN * LW;   // 32768 total rows
constexpr int QKVC  = 384;    // qkv columns
constexpr float SCALE = 0.17677669529663687f;  // 1/sqrt(32)

__device__ inline float dot4(const float4 a, const float4 b) {
  return a.x * b.x + a.y * b.y + a.z * b.z + a.w * b.w;
}

// ---------------- RPE gather: rpe_g[h][i4*64+j4][0:96] ----------------
// s in [0,32): scale*q_rpe   [32,64): k_rpe   [64,96): v_rpe
__global__ __launch_bounds__(256) void rpe_gather_kernel(
    const float* __restrict__ tab, const int* __restrict__ rel_idx,
    float* __restrict__ out)
{
  int gid = blockIdx.x * 256 + threadIdx.x;   // 4*4096*96 = 1,572,864 exact
  int s   = gid % 96;
  int hp  = gid / 96;
  int p   = hp & 4095;
  int h   = hp >> 12;
  float v = tab[(size_t)rel_idx[p] * 384 + h * 96 + s];
  if (s < 32) v *= SCALE;
  out[gid] = v;
}

// ---------------- C[M,N] = A[M,K] @ W[N,K]^T + bias (LDS dbuf v3) -----------
// BM=BN=128, BK=8, 256 threads, 8x8 micro-tile.
// LDS tiles transposed [k][phys(m)], phys(m)=m+(m>>5)*4. No launch-bounds cap
// (v2's 64-VGPR spill lesson).
template <int N, int K>
__global__ __launch_bounds__(256) void gemm_nt_bias_v3(
    const float* __restrict__ A, const float* __restrict__ W,
    const float* __restrict__ bias, float* __restrict__ C)
{
  constexpr int BK  = 8;
  constexpr int NS  = K / BK;
  constexpr int LDP = 144;
  __shared__ float As[2][BK][LDP];
  __shared__ float Ws[2][BK][LDP];

  const int tid  = threadIdx.x;
  const int tx   = tid & 15;          // n-dir, 8 cols each
  const int ty   = tid >> 4;          // m-dir, 8 rows each
  const int srow = tid >> 1;          // staging row 0..127
  const int skk  = (tid & 1) << 2;    // staging k base: 0 or 4
  const int sphys = srow + ((srow >> 5) << 2);

  const float* Ag = A + ((size_t)blockIdx.x * 128 + srow) * K + skk;
  const float* Wg = W + ((size_t)blockIdx.y * 128 + srow) * K + skk;

  float4 ra = *(const float4*)(Ag);
  float4 rw = *(const float4*)(Wg);
  As[0][skk + 0][sphys] = ra.x; As[0][skk + 1][sphys] = ra.y;
  As[0][skk + 2][sphys] = ra.z; As[0][skk + 3][sphys] = ra.w;
  Ws[0][skk + 0][sphys] = rw.x; Ws[0][skk + 1][sphys] = rw.y;
  Ws[0][skk + 2][sphys] = rw.z; Ws[0][skk + 3][sphys] = rw.w;
  __syncthreads();

  const int mA = ty * 8; const int pA = mA + ((mA >> 5) << 2);
  const int mB = tx * 8; const int pB = mB + ((mB >> 5) << 2);

  float acc[8][8] = {};

  for (int s = 0; s < NS; ++s) {
    const int cur = s & 1;
    if (s + 1 < NS) {
      const int k0 = (s + 1) * BK;
      ra = *(const float4*)(Ag + k0);
      rw = *(const float4*)(Wg + k0);
    }
#pragma unroll
    for (int k = 0; k < BK; ++k) {
      float4 a0 = *(const float4*)&As[cur][k][pA];
      float4 a1 = *(const float4*)&As[cur][k][pA + 4];
      float4 b0 = *(const float4*)&Ws[cur][k][pB];
      float4 b1 = *(const float4*)&Ws[cur][k][pB + 4];
      float av[8] = {a0.x, a0.y, a0.z, a0.w, a1.x, a1.y, a1.z, a1.w};
      float bv[8] = {b0.x, b0.y, b0.z, b0.w, b1.x, b1.y, b1.z, b1.w};
#pragma unroll
      for (int i = 0; i < 8; ++i)
#pragma unroll
        for (int j = 0; j < 8; ++j)
          acc[i][j] += av[i] * bv[j];
    }
    if (s + 1 < NS) {
      const int nxt = (s + 1) & 1;
      As[nxt][skk + 0][sphys] = ra.x; As[nxt][skk + 1][sphys] = ra.y;
      As[nxt][skk + 2][sphys] = ra.z; As[nxt][skk + 3][sphys] = ra.w;
      Ws[nxt][skk + 0][sphys] = rw.x; Ws[nxt][skk + 1][sphys] = rw.y;
      Ws[nxt][skk + 2][sphys] = rw.z; Ws[nxt][skk + 3][sphys] = rw.w;
      __syncthreads();
    }
  }

  const int crow = blockIdx.x * 128 + ty * 8;
  const int ccol = blockIdx.y * 128 + tx * 8;
  float4 bb0 = *(const float4*)(bias + ccol);
  float4 bb1 = *(const float4*)(bias + ccol + 4);
#pragma unroll
  for (int i = 0; i < 8; ++i) {
    float4 r0, r1;
    r0.x = acc[i][0] + bb0.x; r0.y = acc[i][1] + bb0.y;
    r0.z = acc[i][2] + bb0.z; r0.w = acc[i][3] + bb0.w;
    r1.x = acc[i][4] + bb1.x; r1.y = acc[i][5] + bb1.y;
    r1.z = acc[i][6] + bb1.z; r1.w = acc[i][7] + bb1.w;
    *(float4*)(C + (size_t)(crow + i) * N + ccol)     = r0;
    *(float4*)(C + (size_t)(crow + i) * N + ccol + 4) = r1;
  }
}

// ---------------- fused window attention v6: scalar-pipe K/V ---------------
// grid (NWIN, 4 heads), 512 threads: thread = (row, jhalf).
// KEY: K/V addresses are wave-uniform (j-loop uniform, jh laundered through
// readfirstlane) -> compiler emits s_load into SGPRs; dot/accum FMAs take the
// K/V operand from SGPRs. This removes ALL K/V LDS staging + the 64
// ds_read_b128/j4/wave that throttled R3-R5 on the LDS pipe, and frees LDS so
// two 512-thread blocks fit per CU (16 waves/CU vs 8 before).
// Softmax stays max-free (scores O(0.1); masked -1e9 -> exp underflows to 0);
// jhalf partials merge by pure summation through a 34 KB LDS scratch.
__global__ __launch_bounds__(512) void attn_kernel(
    const float* __restrict__ qkv, const float* __restrict__ rpeg,
    const float* __restrict__ mask, float* __restrict__ out)
{
  __shared__ float ms[256 * 33];       // merge scratch, stride 33 (conflict-free)
  const int b = blockIdx.x;
  const int h = blockIdx.y;
  const int tid = threadIdx.x;
  const int row = tid & 255;
  // wave-uniform in fact; launder so uniformity analysis keeps K/V scalar
  const int jh  = __builtin_amdgcn_readfirstlane(tid >> 8);
  const size_t rowbase = (size_t)b * LW;

  // uniform K/V base: K row j at kvbase + j*QKVC, V at +128 more floats
  const float* kvbase = qkv + rowbase * QKVC + 128 + h * HD;

  float4 q[8];
  {
    const float4* qr = (const float4*)(qkv + (rowbase + row) * QKVC + h * HD);
#pragma unroll
    for (int d = 0; d < 8; ++d) {
      float4 t = qr[d];
      q[d] = make_float4(t.x * SCALE, t.y * SCALE, t.z * SCALE, t.w * SCALE);
    }
  }
  const float4* rp4base =
      (const float4*)(rpeg + ((size_t)h * 4096 + (size_t)(row >> 2) * 64) * 96);
  const float* mrow = mask + ((size_t)b * LW + row) * LW;

  float4 acc[8];
#pragma unroll
  for (int d = 0; d < 8; ++d) acc[d] = make_float4(0.f, 0.f, 0.f, 0.f);
  float l_run = 0.f;
  const int jbase = jh << 5;

  for (int l = 0; l < 32; ++l) {
    const int j4 = jbase + l;                 // uniform
    const float4* rp = rp4base + j4 * 24;     // sq_rpe[0:8]|k_rpe[8:16]|v_rpe[16:24]
    float4 uq[8];
    float c0 = 0.f;
#pragma unroll
    for (int d = 0; d < 8; ++d) {
      float4 sq = rp[d];
      float4 kr = rp[8 + d];
      uq[d] = make_float4(q[d].x + sq.x, q[d].y + sq.y,
                          q[d].z + sq.z, q[d].w + sq.w);
      c0 += dot4(q[d], kr);
    }
    float4 mv = *(const float4*)(mrow + j4 * 4);
    const float* kj0 = kvbase + (size_t)(j4 * 4) * QKVC;   // uniform
    float s[4] = {mv.x + c0, mv.y + c0, mv.z + c0, mv.w + c0};
#pragma unroll
    for (int jc = 0; jc < 4; ++jc) {
      const float4* kj = (const float4*)(kj0 + jc * QKVC); // uniform -> s_load
      float sa = 0.f;
#pragma unroll
      for (int d = 0; d < 8; ++d) sa += dot4(uq[d], kj[d]);
      s[jc] += sa;
    }
    float p[4];
    p[0] = __expf(s[0]); p[1] = __expf(s[1]);
    p[2] = __expf(s[2]); p[3] = __expf(s[3]);
    float pool = (p[0] + p[1]) + (p[2] + p[3]);
    l_run += pool;
#pragma unroll
    for (int jc = 0; jc < 4; ++jc) {
      const float4* vj = (const float4*)(kj0 + jc * QKVC + 128); // uniform V
      float pj = p[jc];
#pragma unroll
      for (int d = 0; d < 8; ++d) {
        acc[d].x += pj * vj[d].x; acc[d].y += pj * vj[d].y;
        acc[d].z += pj * vj[d].z; acc[d].w += pj * vj[d].w;
      }
    }
#pragma unroll
    for (int d = 0; d < 8; ++d) {
      float4 vr = rp[16 + d];
      acc[d].x += pool * vr.x; acc[d].y += pool * vr.y;
      acc[d].z += pool * vr.z; acc[d].w += pool * vr.w;
    }
  }

  // merge halves via LDS (addr = row*33 + c -> bank (row+c)%32, conflict-free)
  __syncthreads();
  if (jh == 1) {
    float* dst = &ms[row * 33];
#pragma unroll
    for (int d = 0; d < 8; ++d) {
      dst[d * 4 + 0] = acc[d].x; dst[d * 4 + 1] = acc[d].y;
      dst[d * 4 + 2] = acc[d].z; dst[d * 4 + 3] = acc[d].w;
    }
    dst[32] = l_run;
  }
  __syncthreads();
  if (jh == 0) {
    const float* src = &ms[row * 33];
    float inv = 1.f / (l_run + src[32]);
    float4* orow = (float4*)(out + (rowbase + row) * (4 * HD) + h * HD);
#pragma unroll
    for (int d = 0; d < 8; ++d) {
      float4 r;
      r.x = (acc[d].x + src[d * 4 + 0]) * inv;
      r.y = (acc[d].y + src[d * 4 + 1]) * inv;
      r.z = (acc[d].z + src[d * 4 + 2]) * inv;
      r.w = (acc[d].w + src[d * 4 + 3]) * inv;
      orow[d] = r;
    }
  }
}

extern "C" void kernel_launch(void* const* d_in, const int* in_sizes, int n_in,
                              void* d_out, int out_size, void* d_ws, size_t ws_size,
                              hipStream_t stream) {
  (void)in_sizes; (void)n_in; (void)out_size; (void)ws_size;
  const float* x         = (const float*)d_in[0];
  const float* qkv_w     = (const float*)d_in[1];
  const float* qkv_b     = (const float*)d_in[2];
  const float* rpe_table = (const float*)d_in[3];
  const float* proj_w    = (const float*)d_in[4];
  const float* proj_b    = (const float*)d_in[5];
  const float* attn_mask = (const float*)d_in[6];
  const int*   rel_idx   = (const int*)d_in[7];
  float* out = (float*)d_out;

  float* qkvbuf = (float*)d_ws;                          // 32768*384 fp32 (50.3 MB)
  float* rpeg   = qkvbuf + (size_t)ROWS * QKVC;          // 4*4096*96  (6.3 MB)
  float* attnb  = rpeg + (size_t)4 * 4096 * 96;          // 32768*128  (16.8 MB)

  hipLaunchKernelGGL(rpe_gather_kernel, dim3(6144), dim3(256), 0, stream,
                     rpe_table, rel_idx, rpeg);
  hipLaunchKernelGGL((gemm_nt_bias_v3<QKVC, 128>), dim3(ROWS / 128, QKVC / 128),
                     dim3(256), 0, stream, x, qkv_w, qkv_b, qkvbuf);
  hipLaunchKernelGGL(attn_kernel, dim3(NWIN, 4), dim3(512), 0, stream,
                     qkvbuf, rpeg, attn_mask, attnb);
  hipLaunchKernelGGL((gemm_nt_bias_v3<128, 128>), dim3(ROWS / 128, 1),
                     dim3(256), 0, stream, attnb, proj_w, proj_b, out);
}

// Round 7
// 325.925 us; speedup vs baseline: 1.3217x; 1.1293x over previous
//
#include <hip/hip_runtime.h>
#include <math.h>

constexpr int HD    = 32;     // head dim
constexpr int LW    = 256;    // tokens per window (M * N_CAND)
constexpr int NWIN  = 128;    // number of windows (= B_)
constexpr int ROWS  = NWIN * LW;   // 32768 total rows
constexpr int QKVC  = 384;    // qkv columns
constexpr float SCALE = 0.17677669529663687f;  // 1/sqrt(32)

typedef __attribute__((ext_vector_type(8))) short short8;
typedef __attribute__((ext_vector_type(4))) float f32x4;
union I4S8 { int4 i; short8 s; };

__device__ inline float dot4(const float4 a, const float4 b) {
  return a.x * b.x + a.y * b.y + a.z * b.z + a.w * b.w;
}

__device__ inline unsigned short f2bf(float f) {
  unsigned u = __float_as_uint(f);
  unsigned r = (u + 0x7FFFu + ((u >> 16) & 1u)) >> 16;
  return (unsigned short)r;
}

// ---------------- casts ----------------
__global__ __launch_bounds__(256) void cast_x4_kernel(
    const float* __restrict__ in, unsigned short* __restrict__ out, int n4)
{
  int i = blockIdx.x * 256 + threadIdx.x;
  if (i >= n4) return;
  float4 v = ((const float4*)in)[i];
  ushort4 o;
  o.x = f2bf(v.x); o.y = f2bf(v.y); o.z = f2bf(v.z); o.w = f2bf(v.w);
  ((ushort4*)out)[i] = o;
}

// ---------------- RPE gather: rpe_g[h][i4*64+j4][0:96] ----------------
// s in [0,32): scale*q_rpe   [32,64): k_rpe   [64,96): v_rpe
__global__ __launch_bounds__(256) void rpe_gather_kernel(
    const float* __restrict__ tab, const int* __restrict__ rel_idx,
    float* __restrict__ out)
{
  int gid = blockIdx.x * 256 + threadIdx.x;   // 4*4096*96 = 1,572,864 exact
  int s   = gid % 96;
  int hp  = gid / 96;
  int p   = hp & 4095;
  int h   = hp >> 12;
  float v = tab[(size_t)rel_idx[p] * 384 + h * 96 + s];
  if (s < 32) v *= SCALE;
  out[gid] = v;
}

// ---------------- bf16 MFMA GEMM: C[M,N] = A[M,128] @ W[N,128]^T + bias ----
// 128x128 tile, 256 thr / 4 waves, mfma_f32_16x16x32_bf16 (K=32/step).
// Frags: A[m=lane&15][k=quad*8+j], B[n=lane&15][k=quad*8+j] -> direct 16B
// row-major loads. C/D: row=quad*4+reg, col=lane&15 (m89/m91-verified).
// LDS rows padded to 56 bf16 = 112 B (16B-aligned, 2-way banks = free).
template <int N>
__global__ __launch_bounds__(256) void gemm_mfma_bt(
    const unsigned short* __restrict__ A, const unsigned short* __restrict__ W,
    const float* __restrict__ bias, float* __restrict__ C)
{
  constexpr int K   = 128;
  constexpr int LDI = 28;                // ints per LDS row (56 bf16)
  __shared__ int As[128 * LDI];
  __shared__ int Bs[128 * LDI];
  const int tid  = threadIdx.x;
  const int wave = tid >> 6;
  const int lane = tid & 63;
  const int lm   = lane & 15;
  const int q    = lane >> 4;
  const int m0   = blockIdx.x * 128;
  const int n0   = blockIdx.y * 128;

  const int* Ag = (const int*)(A + (size_t)m0 * K);   // 64 ints per row
  const int* Wg = (const int*)(W + (size_t)n0 * K);

  const int srow = tid >> 2;             // 0..63 (+64 for second half)
  const int sk4  = (tid & 3) * 4;        // int offset in 16-int k-slab

  f32x4 acc[2][8] = {};

  for (int ks = 0; ks < 4; ++ks) {
    const int goff = ks * 16 + sk4;
    int4 a0 = *(const int4*)(Ag + (size_t)srow * 64 + goff);
    int4 a1 = *(const int4*)(Ag + (size_t)(srow + 64) * 64 + goff);
    int4 w0 = *(const int4*)(Wg + (size_t)srow * 64 + goff);
    int4 w1 = *(const int4*)(Wg + (size_t)(srow + 64) * 64 + goff);
    *(int4*)&As[srow * LDI + sk4]        = a0;
    *(int4*)&As[(srow + 64) * LDI + sk4] = a1;
    *(int4*)&Bs[srow * LDI + sk4]        = w0;
    *(int4*)&Bs[(srow + 64) * LDI + sk4] = w1;
    __syncthreads();

    short8 af[2], bf[8];
#pragma unroll
    for (int t = 0; t < 2; ++t) {
      const int m = (wave * 2 + t) * 16 + lm;
      I4S8 u; u.i = *(const int4*)&As[m * LDI + q * 4];
      af[t] = u.s;
    }
#pragma unroll
    for (int nt = 0; nt < 8; ++nt) {
      const int n = nt * 16 + lm;
      I4S8 u; u.i = *(const int4*)&Bs[n * LDI + q * 4];
      bf[nt] = u.s;
    }
#pragma unroll
    for (int t = 0; t < 2; ++t)
#pragma unroll
      for (int nt = 0; nt < 8; ++nt)
        acc[t][nt] = __builtin_amdgcn_mfma_f32_16x16x32_bf16(
            af[t], bf[nt], acc[t][nt], 0, 0, 0);
    __syncthreads();
  }

#pragma unroll
  for (int t = 0; t < 2; ++t) {
    const int mrow = m0 + (wave * 2 + t) * 16 + q * 4;
#pragma unroll
    for (int nt = 0; nt < 8; ++nt) {
      const int col = n0 + nt * 16 + lm;
      const float bb = bias[col];
#pragma unroll
      for (int r = 0; r < 4; ++r)
        C[(size_t)(mrow + r) * N + col] = acc[t][nt][r] + bb;
    }
  }
}

// ---------------- fused window attention (R6 structure, bf16 output) -------
__global__ __launch_bounds__(512) void attn_kernel(
    const float* __restrict__ qkv, const float* __restrict__ rpeg,
    const float* __restrict__ mask, unsigned short* __restrict__ out)
{
  __shared__ float ms[256 * 33];       // merge scratch, stride 33 (conflict-free)
  const int b = blockIdx.x;
  const int h = blockIdx.y;
  const int tid = threadIdx.x;
  const int row = tid & 255;
  const int jh  = __builtin_amdgcn_readfirstlane(tid >> 8);
  const size_t rowbase = (size_t)b * LW;

  const float* kvbase = qkv + rowbase * QKVC + 128 + h * HD;

  float4 q[8];
  {
    const float4* qr = (const float4*)(qkv + (rowbase + row) * QKVC + h * HD);
#pragma unroll
    for (int d = 0; d < 8; ++d) {
      float4 t = qr[d];
      q[d] = make_float4(t.x * SCALE, t.y * SCALE, t.z * SCALE, t.w * SCALE);
    }
  }
  const float4* rp4base =
      (const float4*)(rpeg + ((size_t)h * 4096 + (size_t)(row >> 2) * 64) * 96);
  const float* mrow = mask + ((size_t)b * LW + row) * LW;

  float4 acc[8];
#pragma unroll
  for (int d = 0; d < 8; ++d) acc[d] = make_float4(0.f, 0.f, 0.f, 0.f);
  float l_run = 0.f;
  const int jbase = jh << 5;

  for (int l = 0; l < 32; ++l) {
    const int j4 = jbase + l;
    const float4* rp = rp4base + j4 * 24;
    float4 uq[8];
    float c0 = 0.f;
#pragma unroll
    for (int d = 0; d < 8; ++d) {
      float4 sq = rp[d];
      float4 kr = rp[8 + d];
      uq[d] = make_float4(q[d].x + sq.x, q[d].y + sq.y,
                          q[d].z + sq.z, q[d].w + sq.w);
      c0 += dot4(q[d], kr);
    }
    float4 mv = *(const float4*)(mrow + j4 * 4);
    const float* kj0 = kvbase + (size_t)(j4 * 4) * QKVC;
    float s[4] = {mv.x + c0, mv.y + c0, mv.z + c0, mv.w + c0};
#pragma unroll
    for (int jc = 0; jc < 4; ++jc) {
      const float4* kj = (const float4*)(kj0 + jc * QKVC);
      float sa = 0.f;
#pragma unroll
      for (int d = 0; d < 8; ++d) sa += dot4(uq[d], kj[d]);
      s[jc] += sa;
    }
    float p[4];
    p[0] = __expf(s[0]); p[1] = __expf(s[1]);
    p[2] = __expf(s[2]); p[3] = __expf(s[3]);
    float pool = (p[0] + p[1]) + (p[2] + p[3]);
    l_run += pool;
#pragma unroll
    for (int jc = 0; jc < 4; ++jc) {
      const float4* vj = (const float4*)(kj0 + jc * QKVC + 128);
      float pj = p[jc];
#pragma unroll
      for (int d = 0; d < 8; ++d) {
        acc[d].x += pj * vj[d].x; acc[d].y += pj * vj[d].y;
        acc[d].z += pj * vj[d].z; acc[d].w += pj * vj[d].w;
      }
    }
#pragma unroll
    for (int d = 0; d < 8; ++d) {
      float4 vr = rp[16 + d];
      acc[d].x += pool * vr.x; acc[d].y += pool * vr.y;
      acc[d].z += pool * vr.z; acc[d].w += pool * vr.w;
    }
  }

  __syncthreads();
  if (jh == 1) {
    float* dst = &ms[row * 33];
#pragma unroll
    for (int d = 0; d < 8; ++d) {
      dst[d * 4 + 0] = acc[d].x; dst[d * 4 + 1] = acc[d].y;
      dst[d * 4 + 2] = acc[d].z; dst[d * 4 + 3] = acc[d].w;
    }
    dst[32] = l_run;
  }
  __syncthreads();
  if (jh == 0) {
    const float* src = &ms[row * 33];
    float inv = 1.f / (l_run + src[32]);
    unsigned short* orow = out + (rowbase + row) * 128 + h * HD;
#pragma unroll
    for (int d = 0; d < 8; ++d) {
      ushort4 r;
      r.x = f2bf((acc[d].x + src[d * 4 + 0]) * inv);
      r.y = f2bf((acc[d].y + src[d * 4 + 1]) * inv);
      r.z = f2bf((acc[d].z + src[d * 4 + 2]) * inv);
      r.w = f2bf((acc[d].w + src[d * 4 + 3]) * inv);
      *(ushort4*)(orow + d * 4) = r;
    }
  }
}

extern "C" void kernel_launch(void* const* d_in, const int* in_sizes, int n_in,
                              void* d_out, int out_size, void* d_ws, size_t ws_size,
                              hipStream_t stream) {
  (void)in_sizes; (void)n_in; (void)out_size; (void)ws_size;
  const float* x         = (const float*)d_in[0];
  const float* qkv_w     = (const float*)d_in[1];
  const float* qkv_b     = (const float*)d_in[2];
  const float* rpe_table = (const float*)d_in[3];
  const float* proj_w    = (const float*)d_in[4];
  const float* proj_b    = (const float*)d_in[5];
  const float* attn_mask = (const float*)d_in[6];
  const int*   rel_idx   = (const int*)d_in[7];
  float* out = (float*)d_out;

  float* qkvbuf = (float*)d_ws;                          // 32768*384 f32 (50.3 MB)
  float* rpeg   = qkvbuf + (size_t)ROWS * QKVC;          // 1,572,864 f32 (6.3 MB)
  unsigned short* xbf    = (unsigned short*)(rpeg + (size_t)4 * 4096 * 96);
  unsigned short* qkvwbf = xbf + (size_t)ROWS * 128;     // 49152
  unsigned short* projwbf= qkvwbf + (size_t)QKVC * 128;  // 16384
  unsigned short* attnbf = projwbf + (size_t)128 * 128;  // ROWS*128

  // casts
  hipLaunchKernelGGL(cast_x4_kernel, dim3(ROWS * 128 / 4 / 256), dim3(256), 0,
                     stream, x, xbf, ROWS * 128 / 4);
  hipLaunchKernelGGL(cast_x4_kernel, dim3(48), dim3(256), 0, stream,
                     qkv_w, qkvwbf, QKVC * 128 / 4);
  hipLaunchKernelGGL(cast_x4_kernel, dim3(16), dim3(256), 0, stream,
                     proj_w, projwbf, 128 * 128 / 4);
  hipLaunchKernelGGL(rpe_gather_kernel, dim3(6144), dim3(256), 0, stream,
                     rpe_table, rel_idx, rpeg);

  hipLaunchKernelGGL((gemm_mfma_bt<QKVC>), dim3(ROWS / 128, QKVC / 128),
                     dim3(256), 0, stream, xbf, qkvwbf, qkv_b, qkvbuf);
  hipLaunchKernelGGL(attn_kernel, dim3(NWIN, 4), dim3(512), 0, stream,
                     qkvbuf, rpeg, attn_mask, attnbf);
  hipLaunchKernelGGL((gemm_mfma_bt<128>), dim3(ROWS / 128, 1),
                     dim3(256), 0, stream, attnbf, projwbf, proj_b, out);
}